// Round 8
// baseline (1043.180 us; speedup 1.0000x reference)
//
#include <hip/hip_runtime.h>
#include <type_traits>
#include <cstdint>
#include <cstddef>

#define L_SEQ 4800
#define DMODEL 256
#define BS 8
#define MROWS (BS*L_SEQ)          // 38400
#define PERBATCH (L_SEQ*DMODEL)   // 1228800
#define KVSET 67584               // 65536 KV + 2048 Ksum floats per mode

typedef __attribute__((ext_vector_type(8))) short bfrag8;
typedef __attribute__((ext_vector_type(4))) float floatx4;

// ---------- helpers ----------
__device__ __forceinline__ float bf2f(unsigned short u){
  union { unsigned int i; float f; } x; x.i = ((unsigned int)u) << 16; return x.f;
}
__device__ __forceinline__ unsigned short f2bf(float f){
  union { float f; unsigned int i; } x; x.f = f;
  x.i += 0x7fff + ((x.i >> 16) & 1);   // RNE
  return (unsigned short)(x.i >> 16);
}
__device__ __forceinline__ float phi(float x){
  return x > 0.f ? x + 1.f : __expf(x);
}

// ---------- MFMA GEMM (W1): C[M,N] = relu(A[M,K] @ Bt[N,K]^T), 128x128 tile ----------
template<typename TC, bool RELU>
__global__ __launch_bounds__(256) void gemm_mfma(const unsigned short* __restrict__ A,
                                                 const unsigned short* __restrict__ Bt,
                                                 TC* __restrict__ C, int M, int N, int K){
  __shared__ unsigned short Al[128*32];
  __shared__ unsigned short Bl[128*32];
  const int tid  = threadIdx.x;
  const int lane = tid & 63;
  const int wave = tid >> 6;
  const int row0 = blockIdx.y << 7;
  const int col0 = blockIdx.x << 7;
  const int wr0  = (wave & 1) << 6;
  const int wc0  = (wave >> 1) << 6;

  floatx4 acc[4][4] = {};

  const int i0 = tid, i1 = tid + 256;
  const int r0 = i0 >> 2, s0 = i0 & 3;
  const int r1 = i1 >> 2, s1 = i1 & 3;
  const int m = lane & 15, q = lane >> 4;

  for (int k0 = 0; k0 < K; k0 += 32){
    const unsigned short* ga0 = A  + (size_t)(row0 + r0)*K + k0 + s0*8;
    const unsigned short* ga1 = A  + (size_t)(row0 + r1)*K + k0 + s1*8;
    const unsigned short* gb0 = Bt + (size_t)(col0 + r0)*K + k0 + s0*8;
    const unsigned short* gb1 = Bt + (size_t)(col0 + r1)*K + k0 + s1*8;
    __builtin_amdgcn_global_load_lds((const __attribute__((address_space(1))) unsigned int*)ga0,
        (__attribute__((address_space(3))) unsigned int*)(Al + (size_t)i0*8), 16, 0, 0);
    __builtin_amdgcn_global_load_lds((const __attribute__((address_space(1))) unsigned int*)ga1,
        (__attribute__((address_space(3))) unsigned int*)(Al + (size_t)i1*8), 16, 0, 0);
    __builtin_amdgcn_global_load_lds((const __attribute__((address_space(1))) unsigned int*)gb0,
        (__attribute__((address_space(3))) unsigned int*)(Bl + (size_t)i0*8), 16, 0, 0);
    __builtin_amdgcn_global_load_lds((const __attribute__((address_space(1))) unsigned int*)gb1,
        (__attribute__((address_space(3))) unsigned int*)(Bl + (size_t)i1*8), 16, 0, 0);
    __builtin_amdgcn_s_waitcnt(0);
    __syncthreads();

    bfrag8 af[4], bf[4];
    #pragma unroll
    for (int t = 0; t < 4; t++){
      af[t] = *(const bfrag8*)(Al + (size_t)(wr0 + t*16 + m)*32 + q*8);
      bf[t] = *(const bfrag8*)(Bl + (size_t)(wc0 + t*16 + m)*32 + q*8);
    }
    #pragma unroll
    for (int mt = 0; mt < 4; mt++)
      #pragma unroll
      for (int nt = 0; nt < 4; nt++)
        acc[mt][nt] = __builtin_amdgcn_mfma_f32_16x16x32_bf16(af[mt], bf[nt], acc[mt][nt], 0, 0, 0);
    __syncthreads();
  }

  #pragma unroll
  for (int mt = 0; mt < 4; mt++){
    #pragma unroll
    for (int nt = 0; nt < 4; nt++){
      const int col  = col0 + wc0 + nt*16 + m;
      const int rowb = row0 + wr0 + mt*16 + q*4;
      #pragma unroll
      for (int i = 0; i < 4; i++){
        float v = acc[mt][nt][i];
        if (RELU) v = v > 0.f ? v : 0.f;
        if constexpr (std::is_same<TC,float>::value) C[(size_t)(rowb+i)*N + col] = v;
        else                                         C[(size_t)(rowb+i)*N + col] = f2bf(v);
      }
    }
  }
}

// ---------- fused GEMM (N=256 full-width) with optional LayerNorm epilogue ----------
// Tile: 64 rows x 256 cols, 256 threads (4 waves, wave w = cols w*64..+63).
// EPI 0: bf16 store to Cbf[row*256+col]          (projections)
// EPI 2: LN -> bf16 store Cbf[row*512 + 256+col] (Wm + LN1 -> hcat right half)
// EPI 3: LN -> f32 Cf[row*256+col], set/add      (W2 + LN2 -> macc)
template<int EPI>
__global__ __launch_bounds__(256) void gemm256(const unsigned short* __restrict__ A,
                                               const unsigned short* __restrict__ Bt,
                                               unsigned short* __restrict__ Cbf,
                                               float* __restrict__ Cf,
                                               const float* __restrict__ g,
                                               const float* __restrict__ b,
                                               int K, int add){
  __shared__ unsigned short Al[64*32];     // 4 KB
  __shared__ unsigned short Bl[256*32];    // 16 KB
  __shared__ float red[64*8];              // [row][wave*2 + {sum,sq}]
  __shared__ float rowstat[64*2];          // [row][{mu,rs}]
  const int tid  = threadIdx.x;
  const int lane = tid & 63;
  const int wave = tid >> 6;
  const int row0 = blockIdx.x << 6;
  const int m = lane & 15, q = lane >> 4;
  const int wc0 = wave << 6;

  floatx4 acc[4][4] = {};

  for (int k0 = 0; k0 < K; k0 += 32){
    {
      int r = tid >> 2, s = tid & 3;
      const unsigned short* ga = A + (size_t)(row0 + r)*K + k0 + s*8;
      __builtin_amdgcn_global_load_lds((const __attribute__((address_space(1))) unsigned int*)ga,
          (__attribute__((address_space(3))) unsigned int*)(Al + (size_t)tid*8), 16, 0, 0);
    }
    #pragma unroll
    for (int j = 0; j < 4; j++){
      int ub = tid + (j << 8);
      int r = ub >> 2, s = ub & 3;
      const unsigned short* gb = Bt + (size_t)r*K + k0 + s*8;
      __builtin_amdgcn_global_load_lds((const __attribute__((address_space(1))) unsigned int*)gb,
          (__attribute__((address_space(3))) unsigned int*)(Bl + (size_t)ub*8), 16, 0, 0);
    }
    __builtin_amdgcn_s_waitcnt(0);
    __syncthreads();

    bfrag8 af[4], bf[4];
    #pragma unroll
    for (int t = 0; t < 4; t++){
      af[t] = *(const bfrag8*)(Al + (size_t)(t*16 + m)*32 + q*8);
      bf[t] = *(const bfrag8*)(Bl + (size_t)(wc0 + t*16 + m)*32 + q*8);
    }
    #pragma unroll
    for (int mt = 0; mt < 4; mt++)
      #pragma unroll
      for (int nt = 0; nt < 4; nt++)
        acc[mt][nt] = __builtin_amdgcn_mfma_f32_16x16x32_bf16(af[mt], bf[nt], acc[mt][nt], 0, 0, 0);
    __syncthreads();
  }

  if constexpr (EPI == 0){
    #pragma unroll
    for (int mt = 0; mt < 4; mt++)
      #pragma unroll
      for (int nt = 0; nt < 4; nt++){
        const int col = wc0 + nt*16 + m;
        const int rowb = row0 + mt*16 + q*4;
        #pragma unroll
        for (int i = 0; i < 4; i++)
          Cbf[(size_t)(rowb+i)*256 + col] = f2bf(acc[mt][nt][i]);
      }
  } else {
    // per-row sum / sumsq over all 256 cols
    #pragma unroll
    for (int mt = 0; mt < 4; mt++){
      #pragma unroll
      for (int i = 0; i < 4; i++){
        float s = acc[mt][0][i] + acc[mt][1][i] + acc[mt][2][i] + acc[mt][3][i];
        float s2 = acc[mt][0][i]*acc[mt][0][i] + acc[mt][1][i]*acc[mt][1][i]
                 + acc[mt][2][i]*acc[mt][2][i] + acc[mt][3][i]*acc[mt][3][i];
        #pragma unroll
        for (int o = 1; o < 16; o <<= 1){
          s  += __shfl_xor(s,  o, 64);
          s2 += __shfl_xor(s2, o, 64);
        }
        if (m == 0){
          int lr = mt*16 + q*4 + i;
          red[lr*8 + wave*2 + 0] = s;
          red[lr*8 + wave*2 + 1] = s2;
        }
      }
    }
    __syncthreads();
    if (tid < 64){
      float s  = red[tid*8+0] + red[tid*8+2] + red[tid*8+4] + red[tid*8+6];
      float s2 = red[tid*8+1] + red[tid*8+3] + red[tid*8+5] + red[tid*8+7];
      float mu = s * (1.f/256.f);
      float var = s2 * (1.f/256.f) - mu*mu;
      rowstat[tid*2+0] = mu;
      rowstat[tid*2+1] = rsqrtf(var + 1e-5f);
    }
    __syncthreads();
    float gv[4], bv[4];
    #pragma unroll
    for (int nt = 0; nt < 4; nt++){
      gv[nt] = g[wc0 + nt*16 + m];
      bv[nt] = b[wc0 + nt*16 + m];
    }
    #pragma unroll
    for (int mt = 0; mt < 4; mt++){
      #pragma unroll
      for (int i = 0; i < 4; i++){
        const int lr = mt*16 + q*4 + i;
        const float mu = rowstat[lr*2+0], rs = rowstat[lr*2+1];
        #pragma unroll
        for (int nt = 0; nt < 4; nt++){
          const int col = wc0 + nt*16 + m;
          float y = (acc[mt][nt][i] - mu)*rs*gv[nt] + bv[nt];
          if constexpr (EPI == 2){
            Cbf[(size_t)(row0 + lr)*512 + 256 + col] = f2bf(y);
          } else {
            size_t idx = (size_t)(row0 + lr)*256 + col;
            Cf[idx] = add ? (Cf[idx] + y) : y;
          }
        }
      }
    }
  }
}

// ---------- one-time converts ----------
__global__ __launch_bounds__(256) void wconv(const float* __restrict__ W, unsigned short* __restrict__ Wt,
                                             int kshift, int N){
  int idx = blockIdx.x*256 + threadIdx.x;
  int kk = idx & ((1 << kshift) - 1);
  int nn = idx >> kshift;
  Wt[idx] = f2bf(W[(size_t)kk*N + nn]);
}
__global__ __launch_bounds__(256) void conv_bf16(const float* __restrict__ in, unsigned short* __restrict__ out){
  int i = blockIdx.x*256 + threadIdx.x;
  float4 v = ((const float4*)in)[i];
  ushort4 o; o.x = f2bf(v.x); o.y = f2bf(v.y); o.z = f2bf(v.z); o.w = f2bf(v.w);
  ((ushort4*)out)[i] = o;
}

// ---------- permute materializers ----------
__global__ __launch_bounds__(256) void permute1(const unsigned short* __restrict__ sA, unsigned short* __restrict__ dA,
                                                const unsigned short* __restrict__ sB, unsigned short* __restrict__ dB){
  const unsigned short* s = blockIdx.z ? sB : sA;
  unsigned short*       d = blockIdx.z ? dB : dA;
  __shared__ unsigned short tile[1024];
  const int t = threadIdx.x;
  const size_t base = (size_t)blockIdx.x * 1024;
  #pragma unroll
  for (int i = 0; i < 4; i++) tile[i*256 + t] = s[base + i*256 + t];
  __syncthreads();
  const int pg = ((t & 7) << 5) + (t >> 3);
  #pragma unroll
  for (int i = 0; i < 4; i++) d[base + i*256 + t] = tile[i*256 + pg];
}

__global__ __launch_bounds__(256) void permute2(const unsigned short* __restrict__ sA, unsigned short* __restrict__ dA,
                                                const unsigned short* __restrict__ sB, unsigned short* __restrict__ dB){
  const unsigned short* s = blockIdx.z ? sB : sA;
  unsigned short*       d = blockIdx.z ? dB : dA;
  __shared__ unsigned short tile[64*256];
  const int t = threadIdx.x;
  const int rr0 = blockIdx.x * 64;
  const size_t boff = (size_t)blockIdx.y * PERBATCH;
  #pragma unroll
  for (int i = 0; i < 16; i++){
    int u = i*256 + t;
    *(ushort4*)&tile[u*4] = *(const ushort4*)&s[boff + (size_t)rr0*256 + (size_t)u*4];
  }
  __syncthreads();
  #pragma unroll
  for (int i = 0; i < 8; i++){
    #pragma unroll
    for (int w = 0; w < 2; w++){
      int u = w*256 + t;
      int rr = u >> 3, c4 = (u & 7) << 2;
      ushort4 v = *(const ushort4*)&tile[rr*256 + i*32 + c4];
      *(ushort4*)&d[boff + (size_t)i*153600 + (size_t)rr0*32 + (size_t)u*4] = v;
    }
  }
}

__global__ __launch_bounds__(256) void permute3(const unsigned short* __restrict__ sA, unsigned short* __restrict__ dA,
                                                const unsigned short* __restrict__ sB, unsigned short* __restrict__ dB){
  const unsigned short* s = blockIdx.z ? sB : sA;
  unsigned short*       d = blockIdx.z ? dB : dA;
  __shared__ unsigned short tile[64*258];
  const int t = threadIdx.x;
  const int ll0 = blockIdx.x * 64;
  const size_t boff = (size_t)blockIdx.y * PERBATCH;
  #pragma unroll
  for (int i = 0; i < 32; i++){
    int u = i*256 + t;
    int row = u >> 7, col = (u & 127) << 1;
    *(ushort2*)&tile[row*258 + col] = *(const ushort2*)&s[boff + (size_t)(ll0+row)*256 + col];
  }
  __syncthreads();
  const int cw = t >> 6;
  const int ll = t & 63;
  #pragma unroll
  for (int cc = 0; cc < 256; cc += 4){
    int c = cc + cw;
    int sigma = ((c & 31) << 3) + (c >> 5);
    d[boff + (size_t)sigma*4800 + ll0 + ll] = tile[ll*258 + c];
  }
}

// ---------- attention phase A (contiguous) ----------
__global__ __launch_bounds__(256) void attn_stats(const unsigned short* __restrict__ kq,
                                                  const unsigned short* __restrict__ vq,
                                                  float* __restrict__ KV, float* __restrict__ Ksum){
  const int chunk = blockIdx.x, h = blockIdx.y, n = blockIdx.z;
  const int t = threadIdx.x;
  const int d = t >> 3;
  const int w4 = (t & 7) << 2;
  const size_t boff = (size_t)n * PERBATCH;
  __shared__ float kb[8][32], vb[8][32];
  const int lr = t >> 5, lj = t & 31;
  float a0=0.f, a1=0.f, a2=0.f, a3=0.f, ks=0.f;
  const int s0 = chunk * 240;
  for (int s = s0; s < s0 + 240; s += 8){
    int srci = (s + lr)*256 + (h << 5) + lj;
    kb[lr][lj] = phi(bf2f(kq[boff + srci]));
    vb[lr][lj] = bf2f(vq[boff + srci]);
    __syncthreads();
    #pragma unroll
    for (int r = 0; r < 8; r++){
      float kd = kb[r][d];
      ks += kd;
      a0 += kd * vb[r][w4+0];
      a1 += kd * vb[r][w4+1];
      a2 += kd * vb[r][w4+2];
      a3 += kd * vb[r][w4+3];
    }
    __syncthreads();
  }
  float* kvp = KV + (size_t)((((n<<3)+h)<<5) + d)*32 + w4;
  atomicAdd(kvp+0, a0);
  atomicAdd(kvp+1, a1);
  atomicAdd(kvp+2, a2);
  atomicAdd(kvp+3, a3);
  if ((t & 7) == 0) atomicAdd(Ksum + (((n<<3)+h)<<5) + d, ks);
}

// ---------- attention phase B: 16 rows/block, KV cached in LDS ----------
__global__ __launch_bounds__(256) void attn_apply(const unsigned short* __restrict__ qq,
                                                  const float* __restrict__ KV,
                                                  const float* __restrict__ Ksum,
                                                  unsigned short* __restrict__ msg){
  __shared__ float kvs[8192];
  __shared__ float kss[256];
  __shared__ float Qs[4096];
  const int t = threadIdx.x;
  const int n = blockIdx.y;
  const int row0 = blockIdx.x << 4;
  const size_t boff = (size_t)n * PERBATCH;

  #pragma unroll
  for (int i = 0; i < 32; i++) kvs[i*256 + t] = KV[(size_t)n*8192 + i*256 + t];
  kss[t] = Ksum[n*256 + t];
  #pragma unroll
  for (int r = 0; r < 16; r++)
    Qs[r*256 + t] = phi(bf2f(qq[boff + (size_t)(row0 + r)*256 + t]));
  __syncthreads();

  const int h = t >> 5, w = t & 31;
  const float* kvh = kvs + h*1024;
  const float* ksh = kss + h*32;
  float acc[16], den[16];
  #pragma unroll
  for (int r = 0; r < 16; r++){ acc[r] = 0.f; den[r] = 1e-6f; }

  #pragma unroll
  for (int d4 = 0; d4 < 8; d4++){
    const float k0 = kvh[(d4*4+0)*32 + w];
    const float k1 = kvh[(d4*4+1)*32 + w];
    const float k2 = kvh[(d4*4+2)*32 + w];
    const float k3 = kvh[(d4*4+3)*32 + w];
    const float s0 = ksh[d4*4+0], s1 = ksh[d4*4+1], s2 = ksh[d4*4+2], s3 = ksh[d4*4+3];
    #pragma unroll
    for (int r = 0; r < 16; r++){
      float4 qv = *(const float4*)&Qs[r*256 + h*32 + d4*4];
      acc[r] += qv.x*k0 + qv.y*k1 + qv.z*k2 + qv.w*k3;
      den[r] += qv.x*s0 + qv.y*s1 + qv.z*s2 + qv.w*s3;
    }
  }
  #pragma unroll
  for (int r = 0; r < 16; r++)
    msg[boff + (size_t)(row0 + r)*256 + t] = f2bf(acc[r]/den[r]);
}

// ---------- elementwise ----------
__global__ __launch_bounds__(256) void fill_hcat(const float* __restrict__ x, unsigned short* __restrict__ hcat){
  size_t i = (size_t)blockIdx.x*256 + threadIdx.x;
  hcat[(i >> 8)*512 + (i & 255)] = f2bf(x[i]);
}
__global__ __launch_bounds__(256) void xmid_k(const float* __restrict__ x, const float* __restrict__ macc,
                                              float* __restrict__ xmid, unsigned short* __restrict__ hcat){
  size_t i = (size_t)blockIdx.x*256 + threadIdx.x;
  float v = x[i] + 0.5f*macc[i];
  xmid[i] = v;
  hcat[(i >> 8)*512 + (i & 255)] = f2bf(v);
}
__global__ __launch_bounds__(256) void final_k(float* __restrict__ out, const float* __restrict__ macc){
  size_t i = (size_t)blockIdx.x*256 + threadIdx.x;
  out[i] = out[i] + 0.5f*macc[i];
}
__global__ __launch_bounds__(256) void zero_k(float* __restrict__ p, int n){
  int i = blockIdx.x*256 + threadIdx.x;
  if (i < n) p[i] = 0.f;
}

// ---------- orchestration ----------
extern "C" void kernel_launch(void* const* d_in, const int* in_sizes, int n_in,
                              void* d_out, int out_size, void* d_ws, size_t ws_size,
                              hipStream_t stream){
  const float* x   = (const float*)d_in[0];
  const float* src = (const float*)d_in[1];
  const float* Wq  = (const float*)d_in[2];
  const float* Wk  = (const float*)d_in[3];
  const float* Wv  = (const float*)d_in[4];
  const float* Wm  = (const float*)d_in[5];
  const float* W1  = (const float*)d_in[6];
  const float* W2  = (const float*)d_in[7];
  const float* g1  = (const float*)d_in[8];
  const float* b1  = (const float*)d_in[9];
  const float* g2  = (const float*)d_in[10];
  const float* b2  = (const float*)d_in[11];
  float* out = (float*)d_out;

  char* ws = (char*)d_ws;
  size_t off = 0;
  auto alloc = [&](size_t bytes) -> void* {
    void* p = ws + off;
    off += (bytes + 255) & ~(size_t)255;
    return p;
  };
  unsigned short* qB    = (unsigned short*)alloc((size_t)MROWS*256*2);
  unsigned short* kB    = (unsigned short*)alloc((size_t)MROWS*256*2);
  unsigned short* vB    = (unsigned short*)alloc((size_t)MROWS*256*2);
  unsigned short* hcatB = (unsigned short*)alloc((size_t)MROWS*512*2);
  float* t1   = (float*)alloc((size_t)MROWS*256*4);   // aliases only: srcbf/xbf, qP
  float* macc = (float*)alloc((size_t)MROWS*256*4);   // aliases: kP/vP during stats
  float* KV4  = (float*)alloc((size_t)4*KVSET*4);
  unsigned short* WqT = (unsigned short*)alloc((size_t)256*256*2);
  unsigned short* WkT = (unsigned short*)alloc((size_t)256*256*2);
  unsigned short* WvT = (unsigned short*)alloc((size_t)256*256*2);
  unsigned short* WmT = (unsigned short*)alloc((size_t)256*256*2);
  unsigned short* W1T = (unsigned short*)alloc((size_t)512*512*2);
  unsigned short* W2T = (unsigned short*)alloc((size_t)256*512*2);
  (void)ws_size; (void)in_sizes; (void)n_in; (void)out_size;

  unsigned short* msgB  = kB;
  unsigned short* hidB  = kB;
  unsigned short* srcbf = (unsigned short*)t1;
  unsigned short* xbf   = srcbf + (size_t)MROWS*256;
  unsigned short* qP    = (unsigned short*)t1;
  unsigned short* kP    = (unsigned short*)macc;
  unsigned short* vP    = kP + (size_t)MROWS*256;
  float* xmid = out;

  const dim3 blk(256);

  // one-time converts
  wconv<<<dim3(256),  blk, 0, stream>>>(Wq, WqT, 8, 256);
  wconv<<<dim3(256),  blk, 0, stream>>>(Wk, WkT, 8, 256);
  wconv<<<dim3(256),  blk, 0, stream>>>(Wv, WvT, 8, 256);
  wconv<<<dim3(256),  blk, 0, stream>>>(Wm, WmT, 8, 256);
  wconv<<<dim3(1024), blk, 0, stream>>>(W1, W1T, 9, 512);
  wconv<<<dim3(512),  blk, 0, stream>>>(W2, W2T, 9, 256);
  conv_bf16<<<dim3(9600), blk, 0, stream>>>(src, srcbf);
  conv_bf16<<<dim3(9600), blk, 0, stream>>>(x,   xbf);

  // projections: 64x256 fused kernel, plain bf16 epilogue
  gemm256<0><<<dim3(600), blk, 0, stream>>>(xbf,   WqT, qB, nullptr, nullptr, nullptr, 256, 0);
  gemm256<0><<<dim3(600), blk, 0, stream>>>(srcbf, WkT, kB, nullptr, nullptr, nullptr, 256, 0);
  gemm256<0><<<dim3(600), blk, 0, stream>>>(srcbf, WvT, vB, nullptr, nullptr, nullptr, 256, 0);

  // all-mode stats upfront; permuted k/v in macc space
  zero_k<<<dim3(1056), blk, 0, stream>>>(KV4, 4*KVSET);
  attn_stats<<<dim3(20,8,8), blk, 0, stream>>>(kB, vB, KV4 + 0*KVSET, KV4 + 0*KVSET + 65536);
  permute1<<<dim3(9600,1,2), blk, 0, stream>>>(kB, kP, vB, vP);
  attn_stats<<<dim3(20,8,8), blk, 0, stream>>>(kP, vP, KV4 + 1*KVSET, KV4 + 1*KVSET + 65536);
  permute2<<<dim3(75,8,2),  blk, 0, stream>>>(kB, kP, vB, vP);
  attn_stats<<<dim3(20,8,8), blk, 0, stream>>>(kP, vP, KV4 + 2*KVSET, KV4 + 2*KVSET + 65536);
  permute3<<<dim3(75,8,2),  blk, 0, stream>>>(kB, kP, vB, vP);
  attn_stats<<<dim3(20,8,8), blk, 0, stream>>>(kP, vP, KV4 + 3*KVSET, KV4 + 3*KVSET + 65536);

  fill_hcat<<<dim3(MROWS), blk, 0, stream>>>(x, hcatB);

  auto run_block = [&](int mode, int add){
    const float* KV   = KV4 + (size_t)mode*KVSET;
    const float* Ksum = KV + 65536;
    const unsigned short* qsrc = qB;
    if (mode == 1){ permute1<<<dim3(9600,1,1), blk, 0, stream>>>(qB, qP, nullptr, nullptr); qsrc = qP; }
    else if (mode == 2){ permute2<<<dim3(75,8,1), blk, 0, stream>>>(qB, qP, nullptr, nullptr); qsrc = qP; }
    else if (mode == 3){ permute3<<<dim3(75,8,1), blk, 0, stream>>>(qB, qP, nullptr, nullptr); qsrc = qP; }
    attn_apply<<<dim3(300,BS), blk, 0, stream>>>(qsrc, KV, Ksum, msgB);
    // Wm GEMM + LN1 fused -> hcat right half (bf16)
    gemm256<2><<<dim3(600), blk, 0, stream>>>(msgB, WmT, hcatB, nullptr, g1, b1, 256, 0);
    // hidden = relu(hcat @ W1) (bf16)
    gemm_mfma<unsigned short, true><<<dim3(4,300), blk, 0, stream>>>(hcatB, W1T, hidB, MROWS, 512, 512);
    // W2 GEMM + LN2 fused -> macc (set/add)
    gemm256<3><<<dim3(600), blk, 0, stream>>>(hidB, W2T, nullptr, macc, g2, b2, 512, add);
  };

  run_block(0, 0);   // m   (identity)
  run_block(1, 1);   // m3  (p13)
  xmid_k<<<dim3(MROWS), blk, 0, stream>>>(x, macc, xmid, hcatB);
  run_block(2, 0);   // m1  (p21)
  run_block(3, 1);   // m2  (p32)
  final_k<<<dim3(MROWS), blk, 0, stream>>>(out, macc);
}